// Round 14
// baseline (51.205 us; speedup 1.0000x reference)
//
#include <hip/hip_runtime.h>
#include <hip/hip_bf16.h>
#include <stdint.h>

#define VOCAB 50257
#define HID 512
#define LABELS 64
#define KSPLIT 4
#define KLEN 128           // HID / KSPLIT
#define TILEV 128
#define BP 136             // B row pitch in ushorts (128 h + 8 pad) = 272 B

typedef __attribute__((ext_vector_type(8))) short bf16x8;
typedef __attribute__((ext_vector_type(4))) float f32x4;

__device__ __forceinline__ ushort f2bf(float x) {
    uint32_t u = __float_as_uint(x);
    return (ushort)((u + 0x7fffu + ((u >> 16) & 1u)) >> 16);   // RNE
}

__device__ __forceinline__ bf16x8 ld_frag(const ushort* p) {  // p 16B-aligned
    union { uint2 u[2]; bf16x8 v; } x;
    x.u[0] = *(const uint2*)(p);
    x.u[1] = *(const uint2*)(p + 4);
    return x.v;
}

// ---------------------------------------------------------------------------
// K0: C[l] = b2[l] + sum_h b1[h] * w2[l][h]  (bias kept exactly in fp32)
// ---------------------------------------------------------------------------
__global__ void bias_combine(const float* __restrict__ b1,
                             const float* __restrict__ w2,
                             const float* __restrict__ b2,
                             float* __restrict__ C)
{
    int l = threadIdx.x;   // 64 threads
    float s = b2[l];
    for (int h = 0; h < HID; h += 4) {
        float4 wv = *(const float4*)&w2[l * HID + h];
        float4 bv = *(const float4*)&b1[h];
        s += wv.x * bv.x + wv.y * bv.y + wv.z * bv.z + wv.w * bv.w;
    }
    C[l] = s;
}

// ---------------------------------------------------------------------------
// K1 (fast path): P[s][v][l] = sum_h w1[h,v]*w2[l,h] via bf16 MFMA 16x16x32.
// A-fragments load DIRECTLY global->regs (lane(lrow,kg) reads 8 values at
// stride VOCAB; 16 lrow-lanes form a 64B coalesced segment). B staged ONCE
// to LDS (bf16, BP=136 -> aligned b128, 2-way banks). ONE barrier per block,
// then waves free-run: per chunk {16 glb loads, 4 ds_read_b128, cvt, 8 MFMA}.
// C-layout/store identical to R13 (hardware-verified pass).
// ---------------------------------------------------------------------------
#define MFMA_B16(a, b, c) __builtin_amdgcn_mfma_f32_16x16x32_bf16(a, b, c, 0, 0, 0)

#define LOADA(ar, vA, ok, c)                                                  \
    {                                                                         \
        const float* g = &w1[(size_t)(hbase + (c) * 32 + kg * 8) * VOCAB + (vA)]; \
        _Pragma("unroll")                                                     \
        for (int j = 0; j < 8; ++j) ar[j] = (ok) ? g[(size_t)j * VOCAB] : 0.f; \
    }

#define PACK8(ar, dst)                                                        \
    {                                                                         \
        union { uint32_t u[4]; bf16x8 v; } _x;                                \
        _Pragma("unroll")                                                     \
        for (int j = 0; j < 4; ++j)                                           \
            _x.u[j] = (uint32_t)f2bf(ar[2 * j]) |                             \
                      ((uint32_t)f2bf(ar[2 * j + 1]) << 16);                  \
        dst = _x.v;                                                           \
    }

#define CHUNK_STEP(c)                                                         \
    {                                                                         \
        float ar0[8], ar1[8];                                                 \
        LOADA(ar0, vA0, ok0, c);                                              \
        LOADA(ar1, vA1, ok1, c);                                              \
        const ushort* bb = &lB[lrow * BP + (c) * 32 + kg * 8];                \
        bf16x8 b0  = ld_frag(bb);                                             \
        bf16x8 b1f = ld_frag(bb + 16 * BP);                                   \
        bf16x8 b2f = ld_frag(bb + 32 * BP);                                   \
        bf16x8 b3f = ld_frag(bb + 48 * BP);                                   \
        bf16x8 a0, a1;                                                        \
        PACK8(ar0, a0);                                                       \
        PACK8(ar1, a1);                                                       \
        acc00 = MFMA_B16(a0, b0, acc00);  acc01 = MFMA_B16(a0, b1f, acc01);   \
        acc02 = MFMA_B16(a0, b2f, acc02); acc03 = MFMA_B16(a0, b3f, acc03);   \
        acc10 = MFMA_B16(a1, b0, acc10);  acc11 = MFMA_B16(a1, b1f, acc11);   \
        acc12 = MFMA_B16(a1, b2f, acc12); acc13 = MFMA_B16(a1, b3f, acc13);   \
    }

#define STORE_ONE(accv, m, n)                                                 \
    {                                                                         \
        int vb = v0 + wv * 32 + (m) * 16 + kg * 4;                            \
        int l  = (n) * 16 + lrow;                                             \
        _Pragma("unroll")                                                     \
        for (int rr = 0; rr < 4; ++rr)                                        \
            if (fullA || (vb + rr) < VOCAB)                                   \
                Pout[(size_t)(vb + rr) * LABELS + l] = accv[rr];              \
    }

__global__ __launch_bounds__(256) void build_mfma(
    const float* __restrict__ w1,   // [HID][VOCAB]
    const float* __restrict__ w2,   // [LABELS][HID]
    float* __restrict__ P)          // [KSPLIT][VOCAB][LABELS]
{
    __shared__ ushort lB[LABELS * BP];     // [l][h] bf16, w2 K-slice (17 KB)

    const int t     = threadIdx.x;
    const int lane  = t & 63;
    const int wv    = t >> 6;       // wave 0..3 -> v-rows wv*32..+31
    const int lrow  = lane & 15;
    const int kg    = lane >> 4;
    const int v0    = blockIdx.x * TILEV;
    const int hbase = blockIdx.y * KLEN;
    float* Pout = P + (size_t)blockIdx.y * VOCAB * LABELS;
    const bool fullA = (v0 + TILEV <= VOCAB);

    const int vA0 = v0 + wv * 32 + lrow;        // A-frag 0 column
    const int vA1 = vA0 + 16;                   // A-frag 1 column
    const bool ok0 = fullA || (vA0 < VOCAB);
    const bool ok1 = fullA || (vA1 < VOCAB);

    // ---- stage B once: 64l x 128h fp32 -> bf16. 8 float4 per thread.
#pragma unroll
    for (int i = 0; i < 8; ++i) {
        int e  = t + 256 * i;       // 0..2047
        int l  = e >> 5;            // 0..63
        int hq = e & 31;            // float4 index within row
        float4 wv4 = *(const float4*)&w2[l * HID + hbase + hq * 4];
        uint32_t p0 = (uint32_t)f2bf(wv4.x) | ((uint32_t)f2bf(wv4.y) << 16);
        uint32_t p1 = (uint32_t)f2bf(wv4.z) | ((uint32_t)f2bf(wv4.w) << 16);
        *(uint32_t*)&lB[l * BP + hq * 4]     = p0;
        *(uint32_t*)&lB[l * BP + hq * 4 + 2] = p1;
    }
    __syncthreads();                // the only barrier

    f32x4 acc00 = {0,0,0,0}, acc01 = {0,0,0,0}, acc02 = {0,0,0,0}, acc03 = {0,0,0,0};
    f32x4 acc10 = {0,0,0,0}, acc11 = {0,0,0,0}, acc12 = {0,0,0,0}, acc13 = {0,0,0,0};

    CHUNK_STEP(0);
    CHUNK_STEP(1);
    CHUNK_STEP(2);
    CHUNK_STEP(3);

    STORE_ONE(acc00, 0, 0); STORE_ONE(acc01, 0, 1);
    STORE_ONE(acc02, 0, 2); STORE_ONE(acc03, 0, 3);
    STORE_ONE(acc10, 1, 0); STORE_ONE(acc11, 1, 1);
    STORE_ONE(acc12, 1, 2); STORE_ONE(acc13, 1, 3);
}

// ---------------------------------------------------------------------------
// K1 fallback (small ws): folded-b1 fp32 single-buffer version (R7, proven).
// ---------------------------------------------------------------------------
__global__ __launch_bounds__(256) void build_partial_folded(
    const float* __restrict__ w1,
    const float* __restrict__ b1,
    const float* __restrict__ w2,
    float* __restrict__ P,
    int klen)
{
    __shared__ float lds_a[32 * 68];
    __shared__ float lds_b[32 * 68];

    const int t     = threadIdx.x;
    const int v0    = blockIdx.x * 64;
    const int hbase = blockIdx.y * klen;
    float* Pout = P + (size_t)blockIdx.y * VOCAB * LABELS;
    const int tx = t & 15;
    const int ty = t >> 4;
    const bool full = (v0 + 64 <= VOCAB);

    float acc[4][4] = {};

    for (int h0 = hbase; h0 < hbase + klen; h0 += 32) {
#pragma unroll
        for (int i = 0; i < 8; ++i) {
            int e   = t + 256 * i;
            int row = e >> 6;
            int col = e & 63;
            int v   = v0 + col;
            float a = (full || v < VOCAB) ? w1[(size_t)(h0 + row) * VOCAB + v] : 0.f;
            lds_a[row * 68 + col] = a + b1[h0 + row];
        }
#pragma unroll
        for (int i = 0; i < 2; ++i) {
            int e   = t + 256 * i;
            int hh4 = e >> 6;
            int l   = e & 63;
            float4 bv = *(const float4*)&w2[l * HID + h0 + hh4 * 4];
            lds_b[(hh4 * 4 + 0) * 68 + l] = bv.x;
            lds_b[(hh4 * 4 + 1) * 68 + l] = bv.y;
            lds_b[(hh4 * 4 + 2) * 68 + l] = bv.z;
            lds_b[(hh4 * 4 + 3) * 68 + l] = bv.w;
        }
        __syncthreads();
#pragma unroll
        for (int hh2 = 0; hh2 < 32; ++hh2) {
            float4 a = *(const float4*)&lds_a[hh2 * 68 + tx * 4];
            float4 b = *(const float4*)&lds_b[hh2 * 68 + ty * 4];
            acc[0][0] += a.x * b.x; acc[0][1] += a.x * b.y; acc[0][2] += a.x * b.z; acc[0][3] += a.x * b.w;
            acc[1][0] += a.y * b.x; acc[1][1] += a.y * b.y; acc[1][2] += a.y * b.z; acc[1][3] += a.y * b.w;
            acc[2][0] += a.z * b.x; acc[2][1] += a.z * b.y; acc[2][2] += a.z * b.z; acc[2][3] += a.z * b.w;
            acc[3][0] += a.w * b.x; acc[3][1] += a.w * b.y; acc[3][2] += a.w * b.z; acc[3][3] += a.w * b.w;
        }
        __syncthreads();
    }

#pragma unroll
    for (int i = 0; i < 4; ++i) {
        int v = v0 + tx * 4 + i;
        if (v < VOCAB) {
            *(float4*)&Pout[(size_t)v * LABELS + ty * 4] =
                make_float4(acc[i][0], acc[i][1], acc[i][2], acc[i][3]);
        }
    }
}

// ---------------------------------------------------------------------------
// K2: out[tok][l] = sum_s P[s][idx[tok]][l] + bias[l]
// ---------------------------------------------------------------------------
__global__ __launch_bounds__(256) void gather_out(
    const int* __restrict__ idx,
    const float* __restrict__ P,
    const float* __restrict__ bias,
    float* __restrict__ out,
    int ntok, int ksplit)
{
    int g   = blockIdx.x * 256 + threadIdx.x;
    int tok = g >> 4;
    int j   = g & 15;
    if (tok >= ntok) return;
    int v = idx[tok];
    float4 s = ((const float4*)bias)[j];
    const float4* p = (const float4*)P + (size_t)v * 16 + j;
    for (int k = 0; k < ksplit; ++k) {
        float4 m = p[(size_t)k * VOCAB * 16];
        s.x += m.x; s.y += m.y; s.z += m.z; s.w += m.w;
    }
    ((float4*)out)[(size_t)tok * 16 + j] = s;
}

// ---------------------------------------------------------------------------
// Fallback (ws too small for any table): direct per-token dot.
// ---------------------------------------------------------------------------
__global__ __launch_bounds__(256) void direct_kernel(
    const int* __restrict__ idx,
    const float* __restrict__ w1,
    const float* __restrict__ b1,
    const float* __restrict__ w2,
    const float* __restrict__ b2,
    float* __restrict__ out,
    int ntok)
{
    int g   = blockIdx.x * 256 + threadIdx.x;
    int tok = g >> 6;
    int l   = g & 63;
    if (tok >= ntok) return;
    int v = idx[tok];
    float acc = b2[l];
    for (int h = 0; h < HID; ++h)
        acc += (w1[(size_t)h * VOCAB + v] + b1[h]) * w2[l * HID + h];
    out[(size_t)tok * 64 + l] = acc;
}

extern "C" void kernel_launch(void* const* d_in, const int* in_sizes, int n_in,
                              void* d_out, int out_size, void* d_ws, size_t ws_size,
                              hipStream_t stream) {
    const int*   idx = (const int*)d_in[0];
    const float* w1  = (const float*)d_in[1];
    const float* b1  = (const float*)d_in[2];
    const float* w2  = (const float*)d_in[3];
    const float* b2  = (const float*)d_in[4];
    float* out = (float*)d_out;
    const int ntok = in_sizes[0];   // 8*4096 = 32768

    const size_t table_bytes = (size_t)VOCAB * LABELS * sizeof(float);  // ~12.9 MB
    const int nblk2 = (ntok * 16 + 255) / 256;                          // 2048

    if (ws_size >= (size_t)KSPLIT * table_bytes + 1024) {
        // fast path: direct-A MFMA build (pure product) + exact fp32 bias
        float* P = (float*)d_ws;
        float* C = (float*)((char*)d_ws + (size_t)KSPLIT * table_bytes);
        bias_combine<<<1, 64, 0, stream>>>(b1, w2, b2, C);
        dim3 grid1((VOCAB + TILEV - 1) / TILEV, KSPLIT);   // 393 x 4 = 1572
        build_mfma<<<grid1, 256, 0, stream>>>(w1, w2, P);
        gather_out<<<nblk2, 256, 0, stream>>>(idx, P, C, out, ntok, KSPLIT);
    } else {
        int ksplit = 0;
        if      (ws_size >= 4 * table_bytes) ksplit = 4;
        else if (ws_size >= 2 * table_bytes) ksplit = 2;
        else if (ws_size >= 1 * table_bytes) ksplit = 1;
        if (ksplit > 0) {
            float* P = (float*)d_ws;
            dim3 grid1((VOCAB + 63) / 64, ksplit);
            build_partial_folded<<<grid1, 256, 0, stream>>>(w1, b1, w2, P, HID / ksplit);
            gather_out<<<nblk2, 256, 0, stream>>>(idx, P, b2, out, ntok, ksplit);
        } else {
            int nblk = (ntok * 64 + 255) / 256;
            direct_kernel<<<nblk, 256, 0, stream>>>(idx, w1, b1, w2, b2, out, ntok);
        }
    }
}